// Round 1
// baseline (830.193 us; speedup 1.0000x reference)
//
#include <hip/hip_runtime.h>
#include <hip/hip_bf16.h>
#include <stdint.h>

// Problem constants
#define S_LEN 4096
#define B_DIM 8
#define E_DIM 1024
#define H_DIM 16
#define M_ROWS (S_LEN * B_DIM)   // 32768
#define N_QKV (3 * E_DIM)        // 3072
#define HB_DIM (H_DIM * B_DIM)   // 128

typedef float f32x4 __attribute__((ext_vector_type(4)));
typedef short bf16x8 __attribute__((ext_vector_type(8)));

#define MFMA16(a, b, c) __builtin_amdgcn_mfma_f32_16x16x32_bf16(a, b, c, 0, 0, 0)

__device__ __forceinline__ short f2bf(float f) {
  __hip_bfloat16 h = __float2bfloat16(f);
  short s;
  __builtin_memcpy(&s, &h, 2);
  return s;
}
__device__ __forceinline__ float bf2f(short b) {
  unsigned u = ((unsigned)(unsigned short)b) << 16;
  float f;
  __builtin_memcpy(&f, &u, 4);
  return f;
}
__device__ __forceinline__ void gl_lds16(const void* g, void* l) {
  __builtin_amdgcn_global_load_lds(
      (const __attribute__((address_space(1))) void*)g,
      (__attribute__((address_space(3))) void*)l, 16, 0, 0);
}

// ---------------------------------------------------------------------------
// K1: cast fp32 -> bf16 for x, w_qkv, w_out, w_f (one thread = 4 elements)
// ---------------------------------------------------------------------------
__global__ __launch_bounds__(256) void cast_all(
    const float* __restrict__ x, const float* __restrict__ wqkv,
    const float* __restrict__ wout, const float* __restrict__ wf,
    short* __restrict__ xb, short* __restrict__ wqb,
    short* __restrict__ wob, short* __restrict__ wfb) {
  const long n_x = (long)M_ROWS * E_DIM;          // 33554432
  const long n_wq = 3L * E_DIM * E_DIM;           // 3145728
  const long n_wo = (long)E_DIM * E_DIM;          // 1048576
  long idx = ((long)blockIdx.x * 256 + threadIdx.x) * 4;
  const float* src;
  short* dst;
  if (idx < n_x) {
    src = x + idx; dst = xb + idx;
  } else if ((idx -= n_x) < n_wq) {
    src = wqkv + idx; dst = wqb + idx;
  } else if ((idx -= n_wq) < n_wo) {
    src = wout + idx; dst = wob + idx;
  } else {
    idx -= n_wo;  // w_f: 4096 elements
    src = wf + idx; dst = wfb + idx;
  }
  float4 v = *(const float4*)src;
  short4 o;
  o.x = f2bf(v.x); o.y = f2bf(v.y); o.z = f2bf(v.z); o.w = f2bf(v.w);
  *(short4*)dst = o;
}

// ---------------------------------------------------------------------------
// K2/K6: C[m,n] = sum_k A[m,k]*B[n,k]; A: MxK bf16 row-major, B: NxK bf16
// row-major. 128x128 tile, BK=64, 256 threads (4 waves, each 64x64),
// global_load_lds width-16 staging. OUT_F32=1 adds bias and stores fp32.
// ---------------------------------------------------------------------------
template <int OUT_F32>
__global__ __launch_bounds__(256) void gemm_bt(
    const short* __restrict__ A, const short* __restrict__ Bm,
    void* __restrict__ Cout, const float* __restrict__ bias, int M, int N,
    int K) {
  __shared__ short As[128 * 64];
  __shared__ short Bs[128 * 64];
  const int t = threadIdx.x;
  const int w = t >> 6, l = t & 63;
  const int q = l >> 4, c = l & 15;
  const int bm = blockIdx.y * 128;
  const int bn = blockIdx.x * 128;

  // staging: flat LDS offset = w*4096 + j*1024 + l*16 -> row = w*32+j*8+(l>>3),
  // colbyte = (l&7)*16 (row stride 128 B = BK*2)
  const int row_a = w * 32 + (l >> 3);
  const int colb = (l & 7) * 16;
  const char* gA = (const char*)(A + (long)(bm + row_a) * K) + colb;
  const char* gB = (const char*)(Bm + (long)(bn + row_a) * K) + colb;
  char* lA = (char*)As + w * 4096 + l * 16;
  char* lB = (char*)Bs + w * 4096 + l * 16;
  const long strideAj = (long)8 * K * 2;  // 8 rows in bytes

  f32x4 acc[4][4];
#pragma unroll
  for (int i = 0; i < 4; i++)
#pragma unroll
    for (int j = 0; j < 4; j++) acc[i][j] = (f32x4){0.f, 0.f, 0.f, 0.f};

  const int mo = (w >> 1) * 64, no = (w & 1) * 64;

  for (int k0 = 0; k0 < K; k0 += 64) {
    __syncthreads();  // previous compute's ds_reads done before overwrite
#pragma unroll
    for (int j = 0; j < 4; j++) {
      gl_lds16(gA + (long)k0 * 2 + j * strideAj, lA + j * 1024);
      gl_lds16(gB + (long)k0 * 2 + j * strideAj, lB + j * 1024);
    }
    __syncthreads();  // drains vmcnt (global_load_lds) before use
#pragma unroll
    for (int kk = 0; kk < 2; kk++) {
      bf16x8 af[4], bfr[4];
#pragma unroll
      for (int mi = 0; mi < 4; mi++)
        af[mi] = *(const bf16x8*)(As + (mo + mi * 16 + c) * 64 + kk * 32 + q * 8);
#pragma unroll
      for (int ni = 0; ni < 4; ni++)
        bfr[ni] = *(const bf16x8*)(Bs + (no + ni * 16 + c) * 64 + kk * 32 + q * 8);
#pragma unroll
      for (int mi = 0; mi < 4; mi++)
#pragma unroll
        for (int ni = 0; ni < 4; ni++)
          acc[mi][ni] = MFMA16(af[mi], bfr[ni], acc[mi][ni]);
    }
  }

  // epilogue: C/D layout col = c, row = q*4 + r
  if (OUT_F32) {
    float* C = (float*)Cout;
#pragma unroll
    for (int ni = 0; ni < 4; ni++) {
      int n = bn + no + ni * 16 + c;
      float bo = bias[n];
#pragma unroll
      for (int mi = 0; mi < 4; mi++)
#pragma unroll
        for (int r = 0; r < 4; r++) {
          int m = bm + mo + mi * 16 + q * 4 + r;
          C[(long)m * N + n] = acc[mi][ni][r] + bo;
        }
    }
  } else {
    short* C = (short*)Cout;
#pragma unroll
    for (int ni = 0; ni < 4; ni++) {
      int n = bn + no + ni * 16 + c;
#pragma unroll
      for (int mi = 0; mi < 4; mi++)
#pragma unroll
        for (int r = 0; r < 4; r++) {
          int m = bm + mo + mi * 16 + q * 4 + r;
          C[(long)m * N + n] = f2bf(acc[mi][ni][r]);
        }
    }
  }
}

// ---------------------------------------------------------------------------
// K3: feature map. Per block: (h, b, 256 s rows); wave handles 64 s.
//   Qp[h,b,s,p]  = relu(q . w_f[p] + b_f[p])           (A=q rows, B=w_f rows)
//   KpT[h,b,p,s] = relu(k . w_f[p] + b_f[p])           (A=w_f rows, B=k rows)
//   VT[h,b,d,s]  = v[s,d]                              (A=identity, B=v rows)
// ---------------------------------------------------------------------------
__global__ __launch_bounds__(256) void feature_kernel(
    const short* __restrict__ qkv, const short* __restrict__ wfb,
    const float* __restrict__ b_f, short* __restrict__ Qp,
    short* __restrict__ KpT, short* __restrict__ VT) {
  const int bx = blockIdx.x;
  const int sblk = bx & 15, b = (bx >> 4) & 7, h = bx >> 7;
  const int t = threadIdx.x, w = t >> 6, l = t & 63;
  const int q = l >> 4, c = l & 15;
  const int s_base = sblk * 256 + w * 64;
  const int hb = h * 8 + b;

  // w_f fragments: lane -> row (ti*16+c), k = kk*32 + q*8 + j. Serve as both
  // A-operand (rows = p) and B-operand (n = p) thanks to identical layouts.
  bf16x8 wf[4][2];
#pragma unroll
  for (int ti = 0; ti < 4; ti++)
#pragma unroll
    for (int kk = 0; kk < 2; kk++)
      wf[ti][kk] = *(const bf16x8*)(wfb + (ti * 16 + c) * 64 + kk * 32 + q * 8);

  float bfc[4];
#pragma unroll
  for (int ni = 0; ni < 4; ni++) bfc[ni] = b_f[ni * 16 + c];

  f32x4 acc[4][4];
  bf16x8 xf[4][2];

  // ---- Phase Q: Qp (s-major) ----
#pragma unroll
  for (int i = 0; i < 4; i++)
#pragma unroll
    for (int j = 0; j < 4; j++) acc[i][j] = (f32x4){0.f, 0.f, 0.f, 0.f};
#pragma unroll
  for (int mi = 0; mi < 4; mi++) {
    long ridx = (long)((s_base + mi * 16 + c) * 8 + b) * N_QKV;
#pragma unroll
    for (int kk = 0; kk < 2; kk++)
      xf[mi][kk] = *(const bf16x8*)(qkv + ridx + h * 64 + kk * 32 + q * 8);
  }
#pragma unroll
  for (int kk = 0; kk < 2; kk++)
#pragma unroll
    for (int mi = 0; mi < 4; mi++)
#pragma unroll
      for (int ni = 0; ni < 4; ni++)
        acc[mi][ni] = MFMA16(xf[mi][kk], wf[ni][kk], acc[mi][ni]);
#pragma unroll
  for (int mi = 0; mi < 4; mi++)
#pragma unroll
    for (int ni = 0; ni < 4; ni++)
#pragma unroll
      for (int r = 0; r < 4; r++) {
        int s = s_base + mi * 16 + q * 4 + r;
        float v = acc[mi][ni][r] + bfc[ni];
        v = fmaxf(v, 0.f);
        Qp[((long)hb * S_LEN + s) * 64 + ni * 16 + c] = f2bf(v);
      }

  // ---- Phase K: KpT (p-major) via operand swap ----
#pragma unroll
  for (int i = 0; i < 4; i++)
#pragma unroll
    for (int j = 0; j < 4; j++) acc[i][j] = (f32x4){0.f, 0.f, 0.f, 0.f};
#pragma unroll
  for (int si = 0; si < 4; si++) {
    long ridx = (long)((s_base + si * 16 + c) * 8 + b) * N_QKV;
#pragma unroll
    for (int kk = 0; kk < 2; kk++)
      xf[si][kk] =
          *(const bf16x8*)(qkv + ridx + E_DIM + h * 64 + kk * 32 + q * 8);
  }
#pragma unroll
  for (int kk = 0; kk < 2; kk++)
#pragma unroll
    for (int pi = 0; pi < 4; pi++)
#pragma unroll
      for (int si = 0; si < 4; si++)
        acc[pi][si] = MFMA16(wf[pi][kk], xf[si][kk], acc[pi][si]);
#pragma unroll
  for (int pi = 0; pi < 4; pi++)
#pragma unroll
    for (int r = 0; r < 4; r++) {
      int p = pi * 16 + q * 4 + r;
      float bb = b_f[p];
#pragma unroll
      for (int si = 0; si < 4; si++) {
        int s = s_base + si * 16 + c;
        float v = acc[pi][si][r] + bb;
        v = fmaxf(v, 0.f);
        KpT[((long)hb * 64 + p) * S_LEN + s] = f2bf(v);
      }
    }

  // ---- Phase V: VT (d-major) via identity-A MFMA (exact passthrough) ----
  bf16x8 id0 = {0, 0, 0, 0, 0, 0, 0, 0}, id1 = {0, 0, 0, 0, 0, 0, 0, 0};
#pragma unroll
  for (int j = 0; j < 8; j++) {
    int k = q * 8 + j;
    id0[j] = (short)((k == c) ? 0x3F80 : 0);
    id1[j] = (short)((k == c + 16) ? 0x3F80 : 0);
  }
#pragma unroll
  for (int i = 0; i < 4; i++)
#pragma unroll
    for (int j = 0; j < 4; j++) acc[i][j] = (f32x4){0.f, 0.f, 0.f, 0.f};
#pragma unroll
  for (int si = 0; si < 4; si++) {
    long ridx = (long)((s_base + si * 16 + c) * 8 + b) * N_QKV;
#pragma unroll
    for (int kc = 0; kc < 2; kc++)
      xf[si][kc] =
          *(const bf16x8*)(qkv + ridx + 2 * E_DIM + h * 64 + kc * 32 + q * 8);
  }
#pragma unroll
  for (int kc = 0; kc < 2; kc++)
#pragma unroll
    for (int si = 0; si < 4; si++) {
      acc[kc * 2 + 0][si] = MFMA16(id0, xf[si][kc], acc[kc * 2 + 0][si]);
      acc[kc * 2 + 1][si] = MFMA16(id1, xf[si][kc], acc[kc * 2 + 1][si]);
    }
#pragma unroll
  for (int dt = 0; dt < 4; dt++)
#pragma unroll
    for (int si = 0; si < 4; si++)
#pragma unroll
      for (int r = 0; r < 4; r++) {
        int d = (dt >> 1) * 32 + (dt & 1) * 16 + q * 4 + r;
        int s = s_base + si * 16 + c;
        VT[((long)hb * 64 + d) * S_LEN + s] = f2bf(acc[dt][si][r]);
      }
}

// ---------------------------------------------------------------------------
// K4: kv (stored transposed: kvT[d][p] = sum_s v[s,d]*k_p[s,p]), fp32 atomics.
// grid (s-chunks=8, hb=128); wave covers 128 s (4 K-steps), block-reduce.
// ---------------------------------------------------------------------------
__global__ __launch_bounds__(256) void kv_kernel(const short* __restrict__ KpT,
                                                 const short* __restrict__ VT,
                                                 float* __restrict__ kvf) {
  const int hb = blockIdx.y, sc = blockIdx.x;
  const int t = threadIdx.x, w = t >> 6, l = t & 63;
  const int q = l >> 4, c = l & 15;
  const int s0 = sc * 512 + w * 128;
  const short* vb = VT + (long)hb * 64 * S_LEN;
  const short* kb = KpT + (long)hb * 64 * S_LEN;

  f32x4 acc[4][4];
#pragma unroll
  for (int i = 0; i < 4; i++)
#pragma unroll
    for (int j = 0; j < 4; j++) acc[i][j] = (f32x4){0.f, 0.f, 0.f, 0.f};

  for (int it = 0; it < 4; it++) {
    int so = s0 + it * 32 + q * 8;
    bf16x8 af[4], bfr[4];
#pragma unroll
    for (int di = 0; di < 4; di++)
      af[di] = *(const bf16x8*)(vb + (long)(di * 16 + c) * S_LEN + so);
#pragma unroll
    for (int pi = 0; pi < 4; pi++)
      bfr[pi] = *(const bf16x8*)(kb + (long)(pi * 16 + c) * S_LEN + so);
#pragma unroll
    for (int di = 0; di < 4; di++)
#pragma unroll
      for (int pi = 0; pi < 4; pi++)
        acc[di][pi] = MFMA16(af[di], bfr[pi], acc[di][pi]);
  }

  __shared__ float red[4][4096];
#pragma unroll
  for (int di = 0; di < 4; di++)
#pragma unroll
    for (int pi = 0; pi < 4; pi++)
#pragma unroll
      for (int r = 0; r < 4; r++)
        red[w][(di * 16 + q * 4 + r) * 64 + pi * 16 + c] = acc[di][pi][r];
  __syncthreads();
  float* dst = kvf + (long)hb * 4096;
  for (int i = 0; i < 16; i++) {
    int idx = i * 256 + t;
    float s = red[0][idx] + red[1][idx] + red[2][idx] + red[3][idx];
    atomicAdd(dst + idx, s);
  }
}

__global__ __launch_bounds__(256) void kv_cast(const float* __restrict__ kvf,
                                               short* __restrict__ kvb) {
  int i = blockIdx.x * 256 + threadIdx.x;  // 524288 total
  kvb[i] = f2bf(kvf[i]);
}

// K4c: k_sum[hb][p] = sum_s KpT[hb][p][s], stored bf16
__global__ __launch_bounds__(256) void ksum_kernel(const short* __restrict__ KpT,
                                                   short* __restrict__ ksum) {
  const int hb = blockIdx.x;
  const int t = threadIdx.x, w = t >> 6, l = t & 63;
  for (int pi = 0; pi < 16; pi++) {
    int p = w * 16 + pi;
    const short* row = KpT + ((long)hb * 64 + p) * S_LEN;
    float s = 0.f;
#pragma unroll
    for (int i = 0; i < 8; i++) {
      bf16x8 v = *(const bf16x8*)(row + i * 512 + l * 8);
#pragma unroll
      for (int j = 0; j < 8; j++) s += bf2f(v[j]);
    }
    for (int off = 32; off > 0; off >>= 1) s += __shfl_down(s, off, 64);
    if (l == 0) ksum[hb * 64 + p] = f2bf(s);
  }
}

// ---------------------------------------------------------------------------
// K5: num = Qp @ kvT^T (K=64), norm via masked-b_frag MFMA column, divide,
// write attn into (S,B,E) bf16 layout.
// ---------------------------------------------------------------------------
__global__ __launch_bounds__(256) void attn_kernel(
    const short* __restrict__ Qp, const short* __restrict__ kvb,
    const short* __restrict__ ksum, short* __restrict__ attn) {
  const int bx = blockIdx.x;
  const int sblk = bx & 15, b = (bx >> 4) & 7, h = bx >> 7;
  const int t = threadIdx.x, w = t >> 6, l = t & 63;
  const int q = l >> 4, c = l & 15;
  const int s_base = sblk * 256 + w * 64;
  const int hb = h * 8 + b;

  bf16x8 bkv[4][2];
#pragma unroll
  for (int ni = 0; ni < 4; ni++)
#pragma unroll
    for (int kk = 0; kk < 2; kk++)
      bkv[ni][kk] = *(const bf16x8*)(kvb + (long)hb * 4096 +
                                     (ni * 16 + c) * 64 + kk * 32 + q * 8);
  bf16x8 bn[2];
  const bf16x8 zfrag = {0, 0, 0, 0, 0, 0, 0, 0};
#pragma unroll
  for (int kk = 0; kk < 2; kk++) {
    bf16x8 v = *(const bf16x8*)(ksum + hb * 64 + kk * 32 + q * 8);
    bn[kk] = (c == 0) ? v : zfrag;
  }

  bf16x8 af[4][2];
#pragma unroll
  for (int mi = 0; mi < 4; mi++)
#pragma unroll
    for (int kk = 0; kk < 2; kk++)
      af[mi][kk] = *(const bf16x8*)(Qp + ((long)hb * S_LEN + s_base + mi * 16 + c) * 64 +
                                    kk * 32 + q * 8);

  f32x4 acc[4][4], accn[4];
#pragma unroll
  for (int i = 0; i < 4; i++) {
    accn[i] = (f32x4){0.f, 0.f, 0.f, 0.f};
#pragma unroll
    for (int j = 0; j < 4; j++) acc[i][j] = (f32x4){0.f, 0.f, 0.f, 0.f};
  }
#pragma unroll
  for (int kk = 0; kk < 2; kk++)
#pragma unroll
    for (int mi = 0; mi < 4; mi++) {
      accn[mi] = MFMA16(af[mi][kk], bn[kk], accn[mi]);
#pragma unroll
      for (int ni = 0; ni < 4; ni++)
        acc[mi][ni] = MFMA16(af[mi][kk], bkv[ni][kk], acc[mi][ni]);
    }

#pragma unroll
  for (int mi = 0; mi < 4; mi++)
#pragma unroll
    for (int r = 0; r < 4; r++) {
      float nv = __shfl(accn[mi][r], l & 48, 64);  // col-0 lane of this quad
      float inv = 1.f / (nv + 1e-8f);
      int s = s_base + mi * 16 + q * 4 + r;
#pragma unroll
      for (int ni = 0; ni < 4; ni++) {
        float v = acc[mi][ni][r] * inv;
        attn[((long)s * 8 + b) * E_DIM + h * 64 + ni * 16 + c] = f2bf(v);
      }
    }
}

// ---------------------------------------------------------------------------
// Launch
// ---------------------------------------------------------------------------
extern "C" void kernel_launch(void* const* d_in, const int* in_sizes, int n_in,
                              void* d_out, int out_size, void* d_ws,
                              size_t ws_size, hipStream_t stream) {
  const float* x = (const float*)d_in[0];
  const float* w_qkv = (const float*)d_in[1];
  const float* w_out = (const float*)d_in[2];
  const float* b_out = (const float*)d_in[3];
  const float* w_f = (const float*)d_in[4];
  const float* b_f = (const float*)d_in[5];

  char* ws = (char*)d_ws;
  // workspace layout (bytes); total ~459 MiB
  constexpr size_t off_xb = 0;                       // 64 MB (aliased by attn)
  constexpr size_t off_wqb = 67108864;               // 6 MB
  constexpr size_t off_wob = off_wqb + 6291456;      // 2 MB
  constexpr size_t off_wfb = off_wob + 2097152;      // 8 KB
  constexpr size_t off_qkv = off_wfb + 8192;         // 192 MB
  constexpr size_t off_Qp = off_qkv + 201326592;     // 64 MB
  constexpr size_t off_KpT = off_Qp + 67108864;      // 64 MB
  constexpr size_t off_VT = off_KpT + 67108864;      // 64 MB
  constexpr size_t off_kvf = off_VT + 67108864;      // 2 MB
  constexpr size_t off_kvb = off_kvf + 2097152;      // 1 MB
  constexpr size_t off_ksum = off_kvb + 1048576;     // 16 KB

  short* xb = (short*)(ws + off_xb);
  short* wqb = (short*)(ws + off_wqb);
  short* wob = (short*)(ws + off_wob);
  short* wfb = (short*)(ws + off_wfb);
  short* qkv = (short*)(ws + off_qkv);
  short* Qp = (short*)(ws + off_Qp);
  short* KpT = (short*)(ws + off_KpT);
  short* VT = (short*)(ws + off_VT);
  float* kvf = (float*)(ws + off_kvf);
  short* kvb = (short*)(ws + off_kvb);
  short* ksum = (short*)(ws + off_ksum);
  short* attn = xb;  // alias: xb dead after QKV GEMM

  // K1: casts (37752832 elements / 4 per thread)
  cast_all<<<36868, 256, 0, stream>>>(x, w_qkv, w_out, w_f, xb, wqb, wob, wfb);

  // K2: qkv = xb @ wqb^T  (M=32768, N=3072, K=1024)
  gemm_bt<0><<<dim3(N_QKV / 128, M_ROWS / 128), 256, 0, stream>>>(
      xb, wqb, qkv, nullptr, M_ROWS, N_QKV, E_DIM);

  // K3: feature maps + transposes
  feature_kernel<<<2048, 256, 0, stream>>>(qkv, wfb, b_f, Qp, KpT, VT);

  // K4: kv accumulation (zero-init kv first; ws is poisoned each call)
  hipMemsetAsync(kvf, 0, (size_t)HB_DIM * 4096 * 4, stream);
  kv_kernel<<<dim3(8, HB_DIM), 256, 0, stream>>>(KpT, VT, kvf);
  kv_cast<<<2048, 256, 0, stream>>>(kvf, kvb);
  ksum_kernel<<<HB_DIM, 256, 0, stream>>>(KpT, ksum);

  // K5: attn = (Qp @ kv) / (Qp . ksum), into (S,B,E) bf16
  attn_kernel<<<2048, 256, 0, stream>>>(Qp, kvb, ksum, attn);

  // K6: out = attn @ w_out^T + b_out  (fp32)
  gemm_bt<1><<<dim3(E_DIM / 128, M_ROWS / 128), 256, 0, stream>>>(
      attn, wob, (float*)d_out, b_out, M_ROWS, E_DIM, E_DIM);
}